// Round 9
// baseline (50.735 us; speedup 1.0000x reference)
//
#include <hip/hip_runtime.h>
#include <math.h>

#define NOUT    10
#define ROWLEN  784            // 28*28
#define WTOT    (NOUT*ROWLEN)  // 7840
#define CHROWS  4              // rows per chunk
#define CHFL    (CHROWS*ROWLEN) // 3136 floats = 12544 B per chunk
#define NCH     16             // chunks per block
#define BROWS   (CHROWS*NCH)   // 64 rows per block

// ws layout: [7840 x ushort bf16 W][10 x float bias @ +15680B]

// ---------------------------------------------------------------------------
// Prep: fold conv+quantum+linear into Weff (10x784, bf16 RNE) + fp32 bias.
// ---------------------------------------------------------------------------
__global__ __launch_bounds__(256)
void quanv_prep(const float* __restrict__ conv_w, // (4,1,2,2)
                const float* __restrict__ conv_b, // (4,)
                const float* __restrict__ q_w,    // (4,4) (out,in)
                const float* __restrict__ lin_w,  // (10,1568)
                const float* __restrict__ lin_b,  // (10,)
                unsigned short* __restrict__ W16, // ws
                float* __restrict__ biasOut)      // ws + 15680B
{
    const int t = threadIdx.x;

    for (int idx = blockIdx.x * 256 + t; idx < WTOT; idx += gridDim.x * 256) {
        const int o = idx / ROWLEN;
        const int j = idx - o * ROWLEN;          // pixel h*28+w
        const int h = j / 28, w = j - h * 28;
        const int p = (h >> 1) * 14 + (w >> 1);  // patch index (196)
        const int k = (h & 1) * 2 + (w & 1);     // pos in 2x2 patch
        float s = 0.f;
        #pragma unroll
        for (int c = 0; c < 4; ++c)              // conv branch
            s += conv_w[c * 4 + k] * lin_w[o * 1568 + c * 196 + p];
        #pragma unroll
        for (int q = 0; q < 4; ++q)              // quantum branch
            s += q_w[q * 4 + k] * lin_w[o * 1568 + 784 + p * 4 + q];
        unsigned int u = __float_as_uint(s);     // RNE to bf16
        u += 0x7fffu + ((u >> 16) & 1u);
        W16[idx] = (unsigned short)(u >> 16);
    }

    if (blockIdx.x == 0) {
        __shared__ float rs[40];                 // rowsum[o][c]
        const int lane = t & 7;
        for (int pair = t >> 3; pair < 40; pair += 32) {
            const int o = pair >> 2, c = pair & 3;
            const float* base = lin_w + o * 1568 + c * 196;
            float s = 0.f;
            #pragma unroll
            for (int p = 0; p < 196; p += 8) {
                const int pp = p + lane;
                if (pp < 196) s += base[pp];
            }
            s += __shfl_xor(s, 1);
            s += __shfl_xor(s, 2);
            s += __shfl_xor(s, 4);
            if (lane == 0) rs[pair] = s;
        }
        __syncthreads();
        if (t < NOUT) {
            float s = lin_b[t];
            #pragma unroll
            for (int c = 0; c < 4; ++c) s += conv_b[c] * rs[t * 4 + c];
            biasOut[t] = s;
        }
    }
}

// ---------------------------------------------------------------------------
// global_load_lds helpers: linear dst (wave-uniform base, HW adds lane*size),
// per-lane global src. Sizes are literal constants as required.
// ---------------------------------------------------------------------------
__device__ __forceinline__ void gl_lds16(const float* g, float* s) {
    __builtin_amdgcn_global_load_lds(
        (const __attribute__((address_space(1))) unsigned int*)g,
        (__attribute__((address_space(3))) unsigned int*)s, 16, 0, 0);
}
__device__ __forceinline__ void gl_lds4(const float* g, float* s) {
    __builtin_amdgcn_global_load_lds(
        (const __attribute__((address_space(1))) unsigned int*)g,
        (__attribute__((address_space(3))) unsigned int*)s, 4, 0, 0);
}

// ---------------------------------------------------------------------------
// Main. x is DMA-staged into double-buffered LDS chunks (4 rows = 12544 B)
// by wave 0 via global_load_lds while all 4 waves compute the current chunk
// (1 row per wave). W bf16 in LDS. __syncthreads drains vmcnt = buffer swap.
// In-flight bytes per CU ~25 KB >> 9.2 KB BDP. LDS total 40.8 KB/block.
// ---------------------------------------------------------------------------
__global__ __launch_bounds__(256)
void quanv_main(const float* __restrict__ x,
                const unsigned short* __restrict__ Wg, // ws (bf16)
                const float* __restrict__ biasG,
                float* __restrict__ out)
{
    __shared__ unsigned short Wl[WTOT];   // 15680 B
    __shared__ float bias[NOUT];
    __shared__ float xbuf[2][CHFL];       // 2 x 12544 B

    const int t    = threadIdx.x;
    const int lane = t & 63;
    const int wv   = t >> 6;           // wave 0..3 -> row within chunk
    const int l    = lane & 15;        // lane in 16-group
    const int oh   = (lane >> 4) & 1;  // output-half: 0 -> outs 0-4, 1 -> 5-9
    const int kh   = lane >> 5;        // K-half: 0 -> k 0-391, 1 -> 392-783

    const size_t rowbase = (size_t)blockIdx.x * BROWS;
    const float* __restrict__ xblk = x + rowbase * ROWLEN;

    // stage chunk 0 into xbuf[0] (wave 0; 12*1024B + 256B)
    if (wv == 0) {
        #pragma unroll
        for (int i = 0; i < 12; ++i)
            gl_lds16(xblk + i * 256 + lane * 4, &xbuf[0][i * 256]);
        gl_lds4(xblk + 3072 + lane, &xbuf[0][3072]);
    }

    {   // W fill (coalesced uint4, from L2)
        const uint4* __restrict__ src = (const uint4*)Wg;
        uint4* dst = (uint4*)Wl;
        #pragma unroll
        for (int i = 0; i < 4; ++i) {
            const int idx = t + 256 * i;
            if (idx < WTOT / 8) dst[idx] = src[idx];
        }
        if (t < NOUT) bias[t] = biasG[t];
    }
    __syncthreads();   // drains wave 0's DMA (vmcnt) + W fill

    const int wb = oh * 5 * ROWLEN;    // this half's W base (elements)
    int b = 0;

    for (int ch = 0; ch < NCH; ++ch) {
        // stage next chunk into the other buffer (no wait; drains at barrier)
        if (wv == 0 && ch + 1 < NCH) {
            const float* src = xblk + (size_t)(ch + 1) * CHFL;
            float* dst = xbuf[b ^ 1];
            #pragma unroll
            for (int i = 0; i < 12; ++i)
                gl_lds16(src + i * 256 + lane * 4, dst + i * 256);
            gl_lds4(src + 3072 + lane, dst + 3072);
        }

        // ---- compute row = rowbase + ch*4 + wv from xbuf[b] ----
        const float* __restrict__ xr = &xbuf[b][wv * ROWLEN + kh * 392];
        const unsigned short* __restrict__ wr = &Wl[wb + kh * 392];

        float acc[5] = {0.f, 0.f, 0.f, 0.f, 0.f};

        // K-half = 392 floats = 98 float4; 16 lanes -> 6 iters + 2-chunk tail
        #pragma unroll
        for (int i = 0; i < 6; ++i) {
            const int fo = 4 * l + 64 * i;
            const float4 a = *(const float4*)(xr + fo);
            #pragma unroll
            for (int o = 0; o < 5; ++o) {
                const uint2 wp = *(const uint2*)(wr + o * ROWLEN + fo);
                const float w0 = __uint_as_float(wp.x << 16);
                const float w1 = __uint_as_float(wp.x & 0xffff0000u);
                const float w2 = __uint_as_float(wp.y << 16);
                const float w3 = __uint_as_float(wp.y & 0xffff0000u);
                acc[o] = fmaf(a.x, w0, fmaf(a.y, w1,
                         fmaf(a.z, w2, fmaf(a.w, w3, acc[o]))));
            }
        }
        if (l < 2) {   // tail: rel floats 384..391
            const int fo = 384 + 4 * l;
            const float4 a = *(const float4*)(xr + fo);
            #pragma unroll
            for (int o = 0; o < 5; ++o) {
                const uint2 wp = *(const uint2*)(wr + o * ROWLEN + fo);
                const float w0 = __uint_as_float(wp.x << 16);
                const float w1 = __uint_as_float(wp.x & 0xffff0000u);
                const float w2 = __uint_as_float(wp.y << 16);
                const float w3 = __uint_as_float(wp.y & 0xffff0000u);
                acc[o] = fmaf(a.x, w0, fmaf(a.y, w1,
                         fmaf(a.z, w2, fmaf(a.w, w3, acc[o]))));
            }
        }

        // reduce: 16-lane butterfly, then K-half combine (xor 32)
        #pragma unroll
        for (int o = 0; o < 5; ++o) {
            acc[o] += __shfl_xor(acc[o], 1);
            acc[o] += __shfl_xor(acc[o], 2);
            acc[o] += __shfl_xor(acc[o], 4);
            acc[o] += __shfl_xor(acc[o], 8);
            acc[o] += __shfl_xor(acc[o], 32);
        }

        // bias + output-half exchange (xor 16)
        float own[5], ex[5];
        #pragma unroll
        for (int o = 0; o < 5; ++o) {
            own[o] = acc[o] + bias[oh * 5 + o];
            ex[o]  = __shfl_xor(own[o], 16);
        }

        float lg[NOUT];
        #pragma unroll
        for (int o = 0; o < 5; ++o) {
            lg[o]     = oh ? ex[o]  : own[o];
            lg[o + 5] = oh ? own[o] : ex[o];
        }

        float m = -1e30f;
        #pragma unroll
        for (int o = 0; o < NOUT; ++o) m = fmaxf(m, lg[o]);
        float s = 0.f;
        #pragma unroll
        for (int o = 0; o < NOUT; ++o) s += expf(lg[o] - m);
        const float lse = m + logf(s);

        if (lane < NOUT) {   // lanes 0-9 (kh=0,oh=0) hold correct lg
            float v = lg[0];
            #pragma unroll
            for (int o = 1; o < NOUT; ++o) v = (lane == o) ? lg[o] : v;
            out[(rowbase + ch * CHROWS + wv) * NOUT + lane] = v - lse;
        }

        __syncthreads();   // next buffer ready (drains wave 0 vmcnt)
        b ^= 1;
    }
}

extern "C" void kernel_launch(void* const* d_in, const int* in_sizes, int n_in,
                              void* d_out, int out_size, void* d_ws, size_t ws_size,
                              hipStream_t stream) {
    const float* x      = (const float*)d_in[0];
    const float* conv_w = (const float*)d_in[1];
    const float* conv_b = (const float*)d_in[2];
    const float* q_w    = (const float*)d_in[3];
    const float* lin_w  = (const float*)d_in[4];
    const float* lin_b  = (const float*)d_in[5];
    float* out = (float*)d_out;

    unsigned short* W16 = (unsigned short*)d_ws;          // 7840 ushort
    float* biasWs       = (float*)((char*)d_ws + 15680);  // 10 floats

    const int rows = in_sizes[0] / ROWLEN;   // 32768

    quanv_prep<<<31, 256, 0, stream>>>(conv_w, conv_b, q_w, lin_w, lin_b,
                                       W16, biasWs);
    quanv_main<<<rows / BROWS, 256, 0, stream>>>(x, W16, biasWs, out);
}

// Round 10
// 32.691 us; speedup vs baseline: 1.5519x; 1.5519x over previous
//
#include <hip/hip_runtime.h>
#include <math.h>

#define NOUT   10
#define ROWLEN 784           // 28*28
#define WTOT   (NOUT*ROWLEN) // 7840

// ws layout: [7840 float W][10 float bias]

// ---------------------------------------------------------------------------
// Prep: fold conv+quantum+linear into Weff (10x784 fp32) + bias, into d_ws.
// ---------------------------------------------------------------------------
__global__ __launch_bounds__(256)
void quanv_prep(const float* __restrict__ conv_w, // (4,1,2,2)
                const float* __restrict__ conv_b, // (4,)
                const float* __restrict__ q_w,    // (4,4) (out,in)
                const float* __restrict__ lin_w,  // (10,1568)
                const float* __restrict__ lin_b,  // (10,)
                float* __restrict__ W)            // ws: [7840 W][10 bias]
{
    const int t = threadIdx.x;

    for (int idx = blockIdx.x * 256 + t; idx < WTOT; idx += gridDim.x * 256) {
        const int o = idx / ROWLEN;
        const int j = idx - o * ROWLEN;          // pixel h*28+w
        const int h = j / 28, w = j - h * 28;
        const int p = (h >> 1) * 14 + (w >> 1);  // patch index (196)
        const int k = (h & 1) * 2 + (w & 1);     // pos in 2x2 patch
        float s = 0.f;
        #pragma unroll
        for (int c = 0; c < 4; ++c)              // conv branch
            s += conv_w[c * 4 + k] * lin_w[o * 1568 + c * 196 + p];
        #pragma unroll
        for (int q = 0; q < 4; ++q)              // quantum branch
            s += q_w[q * 4 + k] * lin_w[o * 1568 + 784 + p * 4 + q];
        W[idx] = s;
    }

    if (blockIdx.x == 0) {
        __shared__ float rs[40];                 // rowsum[o][c]
        const int lane = t & 7;
        for (int pair = t >> 3; pair < 40; pair += 32) {
            const int o = pair >> 2, c = pair & 3;
            const float* base = lin_w + o * 1568 + c * 196;
            float s = 0.f;
            #pragma unroll
            for (int p = 0; p < 196; p += 8) {
                const int pp = p + lane;
                if (pp < 196) s += base[pp];
            }
            s += __shfl_xor(s, 1);
            s += __shfl_xor(s, 2);
            s += __shfl_xor(s, 4);
            if (lane == 0) rs[pair] = s;
        }
        __syncthreads();
        if (t < NOUT) {
            float s = lin_b[t];
            #pragma unroll
            for (int c = 0; c < 4; ++c) s += conv_b[c] * rs[t * 4 + c];
            W[WTOT + t] = s;
        }
    }
}

// ---------------------------------------------------------------------------
// Main. Depth-4 register prefetch on the x stream (the single variable under
// test vs R5/R8's depth-2: distance ~800-1000 cyc covers HBM-miss latency).
// Geometry: 32-lane pair owns 2 adjacent rows; lower 16 lanes accumulate
// outputs 0..4, upper 16 outputs 5..9. fp32 W in LDS (31.4 KB), bias in
// registers. Block 256 thr = 16 rows; grid = 2048.
// __launch_bounds__(256,5): 5 blocks/CU (157 KB LDS), 20 waves/CU,
// VGPR cap 102 >= natural ~85.
// ---------------------------------------------------------------------------
__global__ __launch_bounds__(256, 5)
void quanv_main(const float* __restrict__ x,
                const float* __restrict__ Wg,   // ws
                float* __restrict__ out)
{
    __shared__ float Wl[WTOT];   // 31360 B

    const int t    = threadIdx.x;
    const int lane = t & 63;
    const int wv   = t >> 6;           // wave in block 0..3
    const int l    = lane & 15;        // lane in 16-group
    const int oh   = (lane >> 4) & 1;  // output-half: 0 -> outs 0-4, 1 -> 5-9
    const int pr   = lane >> 5;        // pair in wave 0,1
    const int r0   = blockIdx.x * 16 + wv * 4 + pr * 2;  // rows r0, r0+1

    const float* __restrict__ xr = x + (size_t)r0 * ROWLEN;

    // depth-4 prefetch buffers, issued BEFORE the LDS fill (independent work)
    float4 px[4][2];
    #pragma unroll
    for (int j = 0; j < 4; ++j)
        #pragma unroll
        for (int r = 0; r < 2; ++r)
            px[j][r] = *(const float4*)(xr + r * ROWLEN + 4 * l + 64 * j);

    {   // coalesced LDS fill: 1960 float4 over 256 threads
        const float4* __restrict__ src = (const float4*)Wg;
        float4* dst = (float4*)Wl;
        #pragma unroll
        for (int i = 0; i < 8; ++i) {
            const int idx = t + 256 * i;
            if (idx < WTOT / 4) dst[idx] = src[idx];
        }
    }

    // bias for this half, straight to registers (L2-hot broadcast)
    float bias_r[5];
    #pragma unroll
    for (int o = 0; o < 5; ++o) bias_r[o] = Wg[WTOT + oh * 5 + o];

    __syncthreads();

    float acc[2][5];
    #pragma unroll
    for (int r = 0; r < 2; ++r)
        #pragma unroll
        for (int o = 0; o < 5; ++o) acc[r][o] = 0.f;

    const int wb = oh * 5 * ROWLEN;    // this half's W base (elements)

    // 784 floats = 196 float4 chunks; 16 lanes -> 12 full iters + 4-chunk tail
    #pragma unroll
    for (int i = 0; i < 12; ++i) {
        const int buf = i & 3;         // compile-time after full unroll
        const float4 a0 = px[buf][0];
        const float4 a1 = px[buf][1];

        const int ni = i + 4;          // depth-4 prefetch into consumed buffer
        if (ni < 12) {
            const int nfo = 4 * l + 64 * ni;
            px[buf][0] = *(const float4*)(xr + nfo);
            px[buf][1] = *(const float4*)(xr + ROWLEN + nfo);
        } else if (ni == 12) {         // i==8, buf==0 -> tail into px[0]
            const int tfo = 768 + 4 * (l & 3);
            px[0][0] = *(const float4*)(xr + tfo);
            px[0][1] = *(const float4*)(xr + ROWLEN + tfo);
        }

        const int fo = 4 * l + 64 * i;
        #pragma unroll
        for (int o = 0; o < 5; ++o) {
            const float4 w4 = *(const float4*)&Wl[wb + o * ROWLEN + fo];
            acc[0][o] = fmaf(a0.x, w4.x, fmaf(a0.y, w4.y,
                        fmaf(a0.z, w4.z, fmaf(a0.w, w4.w, acc[0][o]))));
            acc[1][o] = fmaf(a1.x, w4.x, fmaf(a1.y, w4.y,
                        fmaf(a1.z, w4.z, fmaf(a1.w, w4.w, acc[1][o]))));
        }
    }
    // tail: floats 768..783 (in px[0], loaded at i==8); lanes 0..3 only
    if (l < 4) {
        const int fo = 768 + 4 * l;
        #pragma unroll
        for (int o = 0; o < 5; ++o) {
            const float4 w4 = *(const float4*)&Wl[wb + o * ROWLEN + fo];
            acc[0][o] = fmaf(px[0][0].x, w4.x, fmaf(px[0][0].y, w4.y,
                        fmaf(px[0][0].z, w4.z, fmaf(px[0][0].w, w4.w, acc[0][o]))));
            acc[1][o] = fmaf(px[0][1].x, w4.x, fmaf(px[0][1].y, w4.y,
                        fmaf(px[0][1].z, w4.z, fmaf(px[0][1].w, w4.w, acc[1][o]))));
        }
    }

    // butterfly over the 16-lane group: full-row totals on every lane
    #pragma unroll
    for (int r = 0; r < 2; ++r)
        #pragma unroll
        for (int o = 0; o < 5; ++o) {
            acc[r][o] += __shfl_xor(acc[r][o], 1);
            acc[r][o] += __shfl_xor(acc[r][o], 2);
            acc[r][o] += __shfl_xor(acc[r][o], 4);
            acc[r][o] += __shfl_xor(acc[r][o], 8);
        }

    // add own-half bias; exchange with output-half partner (xor 16)
    float own[2][5], ex[2][5];
    #pragma unroll
    for (int r = 0; r < 2; ++r)
        #pragma unroll
        for (int o = 0; o < 5; ++o) {
            own[r][o] = acc[r][o] + bias_r[o];
            ex[r][o]  = __shfl_xor(own[r][o], 16);
        }

    // oh=0 half finishes row r0, oh=1 half finishes row r0+1
    float lg[NOUT];
    #pragma unroll
    for (int o = 0; o < 5; ++o) {
        lg[o]     = oh ? ex[1][o]  : own[0][o];
        lg[o + 5] = oh ? own[1][o] : ex[0][o];
    }

    float m = -1e30f;
    #pragma unroll
    for (int o = 0; o < NOUT; ++o) m = fmaxf(m, lg[o]);
    float s = 0.f;
    #pragma unroll
    for (int o = 0; o < NOUT; ++o) s += expf(lg[o] - m);
    const float lse = m + logf(s);

    if (l < NOUT) {
        float v = lg[0];
        #pragma unroll
        for (int o = 1; o < NOUT; ++o) v = (l == o) ? lg[o] : v;
        out[(size_t)(r0 + oh) * NOUT + l] = v - lse;
    }
}

extern "C" void kernel_launch(void* const* d_in, const int* in_sizes, int n_in,
                              void* d_out, int out_size, void* d_ws, size_t ws_size,
                              hipStream_t stream) {
    const float* x      = (const float*)d_in[0];
    const float* conv_w = (const float*)d_in[1];
    const float* conv_b = (const float*)d_in[2];
    const float* q_w    = (const float*)d_in[3];
    const float* lin_w  = (const float*)d_in[4];
    const float* lin_b  = (const float*)d_in[5];
    float* out = (float*)d_out;
    float* W   = (float*)d_ws;   // 7850 floats

    const int rows = in_sizes[0] / ROWLEN;   // 32768

    quanv_prep<<<31, 256, 0, stream>>>(conv_w, conv_b, q_w, lin_w, lin_b, W);
    quanv_main<<<rows / 16, 256, 0, stream>>>(x, W, out);
}